// Round 1
// baseline (6800.736 us; speedup 1.0000x reference)
//
#include <hip/hip_runtime.h>
#include <hip/hip_bf16.h>

typedef __attribute__((ext_vector_type(8))) short s16x8;
typedef __attribute__((ext_vector_type(4))) float f32x4;
typedef unsigned short u16;

// ---------------- ws layout (bytes) ----------------
// [0,4096)                 : barrier counters (2 pairs, 256B apart)
// [4096, 4096+262144)      : hbuf  [par2][sg4][kbh8][bblk4][kg4][row16][8] bf16
// [1<<19, +33554432)       : xTf   [p2][t1024][kb4][bblk4][kg4][row16][8] bf16
// [.. , +1572864)          : Wf    [l2][gb64][kb12][lane64][8] bf16
// [.. , +8192)             : bsum  [l2][1024] f32
#define WS_HBUF 4096u
#define WS_XTF  (1u<<19)
#define WS_WF   (WS_XTF + 33554432u)
#define WS_BSUM (WS_WF + 1572864u)

__device__ __forceinline__ u16 f2bf(float f) {
  union { float f; unsigned u; } v; v.f = f;
  unsigned r = v.u + 0x7fffu + ((v.u >> 16) & 1u);
  return (u16)(r >> 16);
}

// x [2][64][128][1024] f32 -> xTf fragment-ordered bf16
__global__ __launch_bounds__(256) void prep_x(const float* __restrict__ x,
                                              u16* __restrict__ xTf) {
  unsigned flat = blockIdx.x * 256u + threadIdx.x;
  unsigned t = flat & 1023u; unsigned r1 = flat >> 10;
  unsigned kg = r1 & 3u; r1 >>= 2;
  unsigned kb = r1 & 3u; r1 >>= 2;
  unsigned b  = r1 & 63u; r1 >>= 6;
  unsigned p  = r1;
  const float* xb = x + (((size_t)p*64u + b)*128u)*1024u + t;
  unsigned i0 = kb*32u + kg*8u;
  u16 vals[8];
  #pragma unroll
  for (int j = 0; j < 8; ++j) vals[j] = f2bf(xb[(size_t)(i0 + (unsigned)j)*1024u]);
  unsigned bblk = b >> 4, row = b & 15u;
  size_t off = ((((((size_t)p*1024u + t)*4u + kb)*4u + bblk)*4u + kg)*16u + row)*8u;
  uint4 pk;
  pk.x = (unsigned)vals[0] | ((unsigned)vals[1] << 16);
  pk.y = (unsigned)vals[2] | ((unsigned)vals[3] << 16);
  pk.z = (unsigned)vals[4] | ((unsigned)vals[5] << 16);
  pk.w = (unsigned)vals[6] | ((unsigned)vals[7] << 16);
  *reinterpret_cast<uint4*>(xTf + off) = pk;
}

// Wih [4H,128], Whh [4H,256] -> Wf B-fragment layout: col=lane&15, k=(lane>>4)*8+j
__global__ __launch_bounds__(256) void prep_w(const float* __restrict__ Wih_r,
                                              const float* __restrict__ Whh_r,
                                              const float* __restrict__ Wih_i,
                                              const float* __restrict__ Whh_i,
                                              u16* __restrict__ Wf) {
  unsigned flat = blockIdx.x * 256u + threadIdx.x;  // 98304 total
  unsigned lane = flat & 63u; unsigned r1 = flat >> 6;
  unsigned kb = r1 % 12u; r1 /= 12u;
  unsigned gb = r1 & 63u; r1 >>= 6;
  unsigned l  = r1;
  const float* Wih = l ? Wih_i : Wih_r;
  const float* Whh = l ? Whh_i : Whh_r;
  unsigned col = lane & 15u, kg = lane >> 4;
  unsigned g = gb*16u + col;
  u16 vals[8];
  #pragma unroll
  for (int j = 0; j < 8; ++j) {
    unsigned k = kb*32u + kg*8u + (unsigned)j;
    float w = (k < 128u) ? Wih[(size_t)g*128u + k] : Whh[(size_t)g*256u + (k-128u)];
    vals[j] = f2bf(w);
  }
  size_t off = ((((size_t)l*64u + gb)*12u + kb)*64u + lane)*8u;
  uint4 pk;
  pk.x = (unsigned)vals[0] | ((unsigned)vals[1] << 16);
  pk.y = (unsigned)vals[2] | ((unsigned)vals[3] << 16);
  pk.z = (unsigned)vals[4] | ((unsigned)vals[5] << 16);
  pk.w = (unsigned)vals[6] | ((unsigned)vals[7] << 16);
  *reinterpret_cast<uint4*>(Wf + off) = pk;
}

__global__ __launch_bounds__(256) void prep_b(const float* __restrict__ bih_r,
                                              const float* __restrict__ bhh_r,
                                              const float* __restrict__ bih_i,
                                              const float* __restrict__ bhh_i,
                                              float* __restrict__ bsum) {
  unsigned i = blockIdx.x * 256u + threadIdx.x;  // 2048
  if (i < 1024u) bsum[i] = bih_r[i] + bhh_r[i];
  else           bsum[i] = bih_i[i-1024u] + bhh_i[i-1024u];
}

// Persistent kernel: 64 WGs = (pair p, row-half rh, col-chunk cq)
__global__ __launch_bounds__(256, 1) void lstm_main(const u16* __restrict__ xTf,
                                                    const u16* __restrict__ Wf,
                                                    const float* __restrict__ bsum,
                                                    u16* __restrict__ hbuf,
                                                    unsigned* __restrict__ barrier_cnt,
                                                    float* __restrict__ out) {
  const unsigned tid  = threadIdx.x;
  const unsigned lane = tid & 63u;
  const unsigned v    = tid >> 6;           // wave 0..3
  const unsigned wg   = blockIdx.x;
  const unsigned p  = wg & 1u;
  const unsigned rh = (wg >> 1) & 1u;
  const unsigned cq = wg >> 2;              // 0..15 : h-cols cq*16..+16
  const unsigned which = v >> 1;            // 0 = lstm_r stream, 1 = lstm_i stream
  const unsigned g0 = (v & 1u) * 2u;        // gate pair base
  const unsigned l  = which;
  const unsigned xp = which ? (1u ^ p) : p; // x part for this stream
  const unsigned sg = p*2u + which;         // hbuf stream slot

  __shared__ float gl[4608];     // [which2][gate4][hc16][row pad36]
  __shared__ float hout[1280];   // [which2][row32][hc pad20]
  __shared__ float ob[10240];    // [item512][t pad20]  output staging (16 steps)

  // weights resident in registers: 2 gate-tiles x 12 k-blocks
  s16x8 Bfrag[2][12];
  #pragma unroll
  for (int ct = 0; ct < 2; ++ct) {
    unsigned gb = (g0 + (unsigned)ct)*16u + cq;
    #pragma unroll
    for (int kb = 0; kb < 12; ++kb) {
      size_t off = ((((size_t)l*64u + gb)*12u + (unsigned)kb)*64u + lane)*8u;
      Bfrag[ct][kb] = *reinterpret_cast<const s16x8*>(Wf + off);
    }
  }

  // activation-phase statics
  const unsigned a_s = tid >> 7;            // stream
  const unsigned a_r = tid & 31u;           // local row
  const unsigned a_q = (tid >> 5) & 3u;     // hc quad (4 cols)
  float bias[4][4];
  #pragma unroll
  for (int hq = 0; hq < 4; ++hq) {
    unsigned hc = a_q*4u + (unsigned)hq;
    #pragma unroll
    for (int g = 0; g < 4; ++g)
      bias[hq][g] = bsum[(size_t)a_s*1024u + (unsigned)g*256u + cq*16u + hc];
  }
  float c[4] = {0.f, 0.f, 0.f, 0.f};
  const unsigned a_kbh  = cq >> 1;
  const unsigned a_bblk = rh*2u + (a_r >> 4);
  const unsigned a_row  = a_r & 15u;
  const unsigned a_sg   = p*2u + a_s;
  const unsigned a_kg   = (cq & 1u)*2u + (a_q >> 1);
  const unsigned a_j0   = (a_q & 1u)*4u;

  unsigned* cnt = barrier_cnt + p*64u;      // per-pair counter, separate cachelines

  for (unsigned t = 0; t < 1024u; ++t) {
    const unsigned par = t & 1u;

    // ---- phase 1: A-fragment loads (global, coalesced) + MFMA ----
    f32x4 acc[2][2];
    #pragma unroll
    for (int rt = 0; rt < 2; ++rt)
      #pragma unroll
      for (int ct = 0; ct < 2; ++ct) { f32x4 z = {0.f,0.f,0.f,0.f}; acc[rt][ct] = z; }

    #pragma unroll
    for (int rt = 0; rt < 2; ++rt) {
      const unsigned bblk = rh*2u + (unsigned)rt;
      #pragma unroll
      for (int kb = 0; kb < 12; ++kb) {
        s16x8 afrag;
        if (kb < 4) {
          size_t off = (((((size_t)xp*1024u + t)*4u + (unsigned)kb)*4u + bblk)*512u) + lane*8u;
          afrag = *reinterpret_cast<const s16x8*>(xTf + off);
        } else {
          size_t off = (((((size_t)par*4u + sg)*8u + (unsigned)(kb-4))*4u + bblk)*512u) + lane*8u;
          afrag = *reinterpret_cast<const s16x8*>(hbuf + off);
        }
        acc[rt][0] = __builtin_amdgcn_mfma_f32_16x16x32_bf16(afrag, Bfrag[0][kb], acc[rt][0], 0, 0, 0);
        acc[rt][1] = __builtin_amdgcn_mfma_f32_16x16x32_bf16(afrag, Bfrag[1][kb], acc[rt][1], 0, 0, 0);
      }
    }

    // ---- phase 2: gates -> LDS ----
    #pragma unroll
    for (int rt = 0; rt < 2; ++rt)
      #pragma unroll
      for (int ct = 0; ct < 2; ++ct) {
        unsigned g = g0 + (unsigned)ct;
        unsigned idx = ((which*4u + g)*16u + (lane & 15u))*36u + (unsigned)rt*16u + (lane >> 4)*4u;
        *reinterpret_cast<f32x4*>(&gl[idx]) = acc[rt][ct];
      }
    __syncthreads();

    // ---- phase 3: activations, c/h update, h -> global (bf16) ----
    float hv[4];
    #pragma unroll
    for (int hq = 0; hq < 4; ++hq) {
      unsigned hc = a_q*4u + (unsigned)hq;
      unsigned base = (a_s*4u*16u + hc)*36u + a_r;
      float gi = gl[base + 0u*576u] + bias[hq][0];
      float gf = gl[base + 1u*576u] + bias[hq][1];
      float gg = gl[base + 2u*576u] + bias[hq][2];
      float go = gl[base + 3u*576u] + bias[hq][3];
      float ii = 1.f / (1.f + __expf(-gi));
      float ff = 1.f / (1.f + __expf(-gf));
      float eg = __expf(2.f * gg);
      float tg = 1.f - 2.f / (eg + 1.f);
      float oo = 1.f / (1.f + __expf(-go));
      float cn = ff * c[hq] + ii * tg;
      c[hq] = cn;
      float ec = __expf(2.f * cn);
      float tc = 1.f - 2.f / (ec + 1.f);
      hv[hq] = oo * tc;
    }
    {
      size_t off = ((((((size_t)(par^1u)*4u + a_sg)*8u + a_kbh)*4u + a_bblk)*4u + a_kg)*16u + a_row)*8u + a_j0;
      uint2 pk;
      pk.x = (unsigned)f2bf(hv[0]) | ((unsigned)f2bf(hv[1]) << 16);
      pk.y = (unsigned)f2bf(hv[2]) | ((unsigned)f2bf(hv[3]) << 16);
      *reinterpret_cast<uint2*>(hbuf + off) = pk;
    }
    {
      unsigned hb = (a_s*32u + a_r)*20u + a_q*4u;
      f32x4 hvv = {hv[0], hv[1], hv[2], hv[3]};
      *reinterpret_cast<f32x4*>(&hout[hb]) = hvv;
    }
    __syncthreads();

    // ---- phase 4: pair combine -> LDS output staging ----
    #pragma unroll
    for (int kk = 0; kk < 2; ++kk) {
      unsigned item = tid*2u + (unsigned)kk;
      unsigned r = item >> 4, hc = item & 15u;
      float aV = hout[r*20u + hc];
      float bV = hout[(32u + r)*20u + hc];
      float oV = p ? (aV + bV) : (aV - bV);
      ob[item*20u + (t & 15u)] = oV;
    }

    // ---- flush staged output every 16 steps (coalesced 64B per location) ----
    if ((t & 15u) == 15u) {
      unsigned tb = t >> 4;
      #pragma unroll
      for (int kk = 0; kk < 2; ++kk) {
        unsigned item = tid*2u + (unsigned)kk;
        unsigned r = item >> 4, hc = item & 15u;
        size_t o = (((size_t)p*64u + rh*32u + r)*256u + cq*16u + hc)*1024u + (size_t)tb*16u;
        #pragma unroll
        for (int q = 0; q < 4; ++q)
          *reinterpret_cast<f32x4*>(out + o + (unsigned)q*4u) =
              *reinterpret_cast<f32x4*>(&ob[item*20u + (unsigned)q*4u]);
      }
    }

    // ---- phase 5: grid barrier (per pair, monotonic counter) ----
    __syncthreads();
    if (tid == 0) {
      __threadfence();
      __hip_atomic_fetch_add(cnt, 1u, __ATOMIC_RELEASE, __HIP_MEMORY_SCOPE_AGENT);
      unsigned tgt = 32u * (t + 1u);
      while (__hip_atomic_load(cnt, __ATOMIC_ACQUIRE, __HIP_MEMORY_SCOPE_AGENT) < tgt)
        __builtin_amdgcn_s_sleep(2);
    }
    __syncthreads();
  }
}

extern "C" void kernel_launch(void* const* d_in, const int* in_sizes, int n_in,
                              void* d_out, int out_size, void* d_ws, size_t ws_size,
                              hipStream_t stream) {
  (void)in_sizes; (void)n_in; (void)out_size; (void)ws_size;
  const float* x     = (const float*)d_in[0];
  const float* Wih_r = (const float*)d_in[1];
  const float* Whh_r = (const float*)d_in[2];
  const float* bih_r = (const float*)d_in[3];
  const float* bhh_r = (const float*)d_in[4];
  const float* Wih_i = (const float*)d_in[5];
  const float* Whh_i = (const float*)d_in[6];
  const float* bih_i = (const float*)d_in[7];
  const float* bhh_i = (const float*)d_in[8];
  float* out = (float*)d_out;

  char* ws = (char*)d_ws;
  unsigned* cnt = (unsigned*)(ws + 0);
  u16* hbuf     = (u16*)(ws + WS_HBUF);
  u16* xTf      = (u16*)(ws + WS_XTF);
  u16* Wf       = (u16*)(ws + WS_WF);
  float* bsv    = (float*)(ws + WS_BSUM);

  // zero barrier counters + h0/c-parity buffers
  hipMemsetAsync(ws, 0, WS_HBUF + 262144u, stream);

  prep_x<<<8192, 256, 0, stream>>>(x, xTf);
  prep_w<<<384, 256, 0, stream>>>(Wih_r, Whh_r, Wih_i, Whh_i, Wf);
  prep_b<<<8, 256, 0, stream>>>(bih_r, bhh_r, bih_i, bhh_i, bsv);
  lstm_main<<<64, 256, 0, stream>>>(xTf, Wf, bsv, hbuf, cnt, out);
}

// Round 2
// 4138.029 us; speedup vs baseline: 1.6435x; 1.6435x over previous
//
#include <hip/hip_runtime.h>
#include <hip/hip_bf16.h>

typedef __attribute__((ext_vector_type(8))) short s16x8;
typedef __attribute__((ext_vector_type(4))) float f32x4;
typedef unsigned short u16;
typedef unsigned long long u64;

// ---------------- ws layout (bytes) ----------------
// [0,4096)                 : flags: 4 domains x 64 u32, domain stride 1024B
// [4096, 4096+262144)      : hbuf  [par2][sg4][kbh8][bblk4][kg4][row16][8] bf16
// [1<<19, +33554432)       : xTf   [p2][t1024][kb4][bblk4][kg4][row16][8] bf16
// [.. , +1572864)          : Wf    [l2][gb64][kb12][lane64][8] bf16
// [.. , +8192)             : bsum  [l2][1024] f32
#define WS_HBUF 4096u
#define WS_XTF  (1u<<19)
#define WS_WF   (WS_XTF + 33554432u)
#define WS_BSUM (WS_WF + 1572864u)

__device__ __forceinline__ u16 f2bf(float f) {
  union { float f; unsigned u; } v; v.f = f;
  unsigned r = v.u + 0x7fffu + ((v.u >> 16) & 1u);
  return (u16)(r >> 16);
}

// x [2][64][128][1024] f32 -> xTf fragment-ordered bf16
__global__ __launch_bounds__(256) void prep_x(const float* __restrict__ x,
                                              u16* __restrict__ xTf) {
  unsigned flat = blockIdx.x * 256u + threadIdx.x;
  unsigned t = flat & 1023u; unsigned r1 = flat >> 10;
  unsigned kg = r1 & 3u; r1 >>= 2;
  unsigned kb = r1 & 3u; r1 >>= 2;
  unsigned b  = r1 & 63u; r1 >>= 6;
  unsigned p  = r1;
  const float* xb = x + (((size_t)p*64u + b)*128u)*1024u + t;
  unsigned i0 = kb*32u + kg*8u;
  u16 vals[8];
  #pragma unroll
  for (int j = 0; j < 8; ++j) vals[j] = f2bf(xb[(size_t)(i0 + (unsigned)j)*1024u]);
  unsigned bblk = b >> 4, row = b & 15u;
  size_t off = ((((((size_t)p*1024u + t)*4u + kb)*4u + bblk)*4u + kg)*16u + row)*8u;
  uint4 pk;
  pk.x = (unsigned)vals[0] | ((unsigned)vals[1] << 16);
  pk.y = (unsigned)vals[2] | ((unsigned)vals[3] << 16);
  pk.z = (unsigned)vals[4] | ((unsigned)vals[5] << 16);
  pk.w = (unsigned)vals[6] | ((unsigned)vals[7] << 16);
  *reinterpret_cast<uint4*>(xTf + off) = pk;
}

// Wih [4H,128], Whh [4H,256] -> Wf B-fragment layout: col=lane&15, k=(lane>>4)*8+j
__global__ __launch_bounds__(256) void prep_w(const float* __restrict__ Wih_r,
                                              const float* __restrict__ Whh_r,
                                              const float* __restrict__ Wih_i,
                                              const float* __restrict__ Whh_i,
                                              u16* __restrict__ Wf) {
  unsigned flat = blockIdx.x * 256u + threadIdx.x;  // 98304 total
  unsigned lane = flat & 63u; unsigned r1 = flat >> 6;
  unsigned kb = r1 % 12u; r1 /= 12u;
  unsigned gb = r1 & 63u; r1 >>= 6;
  unsigned l  = r1;
  const float* Wih = l ? Wih_i : Wih_r;
  const float* Whh = l ? Whh_i : Whh_r;
  unsigned col = lane & 15u, kg = lane >> 4;
  unsigned g = gb*16u + col;
  u16 vals[8];
  #pragma unroll
  for (int j = 0; j < 8; ++j) {
    unsigned k = kb*32u + kg*8u + (unsigned)j;
    float w = (k < 128u) ? Wih[(size_t)g*128u + k] : Whh[(size_t)g*256u + (k-128u)];
    vals[j] = f2bf(w);
  }
  size_t off = ((((size_t)l*64u + gb)*12u + kb)*64u + lane)*8u;
  uint4 pk;
  pk.x = (unsigned)vals[0] | ((unsigned)vals[1] << 16);
  pk.y = (unsigned)vals[2] | ((unsigned)vals[3] << 16);
  pk.z = (unsigned)vals[4] | ((unsigned)vals[5] << 16);
  pk.w = (unsigned)vals[6] | ((unsigned)vals[7] << 16);
  *reinterpret_cast<uint4*>(Wf + off) = pk;
}

__global__ __launch_bounds__(256) void prep_b(const float* __restrict__ bih_r,
                                              const float* __restrict__ bhh_r,
                                              const float* __restrict__ bih_i,
                                              const float* __restrict__ bhh_i,
                                              float* __restrict__ bsum) {
  unsigned i = blockIdx.x * 256u + threadIdx.x;  // 2048
  if (i < 1024u) bsum[i] = bih_r[i] + bhh_r[i];
  else           bsum[i] = bih_i[i-1024u] + bhh_i[i-1024u];
}

// Persistent kernel: 64 WGs = (pair p, row-half rh, col-chunk cq)
// Sync: per-(p,rh) domain of 16 WGs x 4 waves; per-wave monotonic step flags
// written/read with relaxed agent-scope atomics (coherent at LLC, no wbl2/inv).
__global__ __launch_bounds__(256, 1) void lstm_main(const u16* __restrict__ xTf,
                                                    const u16* __restrict__ Wf,
                                                    const float* __restrict__ bsum,
                                                    u16* __restrict__ hbuf,
                                                    unsigned* __restrict__ flags,
                                                    float* __restrict__ out) {
  const unsigned tid  = threadIdx.x;
  const unsigned lane = tid & 63u;
  const unsigned v    = tid >> 6;           // wave 0..3
  const unsigned wg   = blockIdx.x;
  const unsigned p  = wg & 1u;
  const unsigned rh = (wg >> 1) & 1u;
  const unsigned cq = wg >> 2;              // 0..15 : h-cols cq*16..+16
  const unsigned which = v >> 1;            // 0 = lstm_r stream, 1 = lstm_i stream
  const unsigned g0 = (v & 1u) * 2u;        // gate pair base
  const unsigned l  = which;
  const unsigned xp = which ? (1u ^ p) : p; // x part for this stream
  const unsigned sg = p*2u + which;         // hbuf stream slot

  unsigned* flagp = flags + (p*2u + rh)*256u;   // domain base (1KB stride)
  const unsigned myflag = cq*4u + v;

  __shared__ float gl[4608];     // [which2][gate4][hc16][row pad36]
  __shared__ float hout[1280];   // [which2][row32][hc pad20]
  __shared__ float ob[10240];    // [item512][t pad20]  output staging (16 steps)

  // weights resident in registers: 2 gate-tiles x 12 k-blocks
  s16x8 Bfrag[2][12];
  #pragma unroll
  for (int ct = 0; ct < 2; ++ct) {
    unsigned gb = (g0 + (unsigned)ct)*16u + cq;
    #pragma unroll
    for (int kb = 0; kb < 12; ++kb) {
      size_t off = ((((size_t)l*64u + gb)*12u + (unsigned)kb)*64u + lane)*8u;
      Bfrag[ct][kb] = *reinterpret_cast<const s16x8*>(Wf + off);
    }
  }

  // activation-phase statics
  const unsigned a_s = tid >> 7;            // stream
  const unsigned a_r = tid & 31u;           // local row
  const unsigned a_q = (tid >> 5) & 3u;     // hc quad (4 cols)
  float bias[4][4];
  #pragma unroll
  for (int hq = 0; hq < 4; ++hq) {
    unsigned hc = a_q*4u + (unsigned)hq;
    #pragma unroll
    for (int g = 0; g < 4; ++g)
      bias[hq][g] = bsum[(size_t)a_s*1024u + (unsigned)g*256u + cq*16u + hc];
  }
  float c[4] = {0.f, 0.f, 0.f, 0.f};
  const unsigned a_kbh  = cq >> 1;
  const unsigned a_bblk = rh*2u + (a_r >> 4);
  const unsigned a_row  = a_r & 15u;
  const unsigned a_sg   = p*2u + a_s;
  const unsigned a_kg   = (cq & 1u)*2u + (a_q >> 1);
  const unsigned a_j0   = (a_q & 1u)*4u;

  // x-fragment prefetch buffer (t=0)
  s16x8 xa[8];
  #pragma unroll
  for (int rt = 0; rt < 2; ++rt) {
    unsigned bblk = rh*2u + (unsigned)rt;
    #pragma unroll
    for (int kb = 0; kb < 4; ++kb) {
      size_t off = (((((size_t)xp*1024u + 0u)*4u + (unsigned)kb)*4u + bblk)*512u) + lane*8u;
      xa[rt*4+kb] = *reinterpret_cast<const s16x8*>(xTf + off);
    }
  }

  for (unsigned t = 0; t < 1024u; ++t) {
    const unsigned par = t & 1u;

    // ---- phase 1a: x MFMAs (no h dependency) ----
    f32x4 acc[2][2];
    #pragma unroll
    for (int rt = 0; rt < 2; ++rt)
      #pragma unroll
      for (int ct = 0; ct < 2; ++ct) { f32x4 z = {0.f,0.f,0.f,0.f}; acc[rt][ct] = z; }

    #pragma unroll
    for (int rt = 0; rt < 2; ++rt)
      #pragma unroll
      for (int kb = 0; kb < 4; ++kb) {
        acc[rt][0] = __builtin_amdgcn_mfma_f32_16x16x32_bf16(xa[rt*4+kb], Bfrag[0][kb], acc[rt][0], 0, 0, 0);
        acc[rt][1] = __builtin_amdgcn_mfma_f32_16x16x32_bf16(xa[rt*4+kb], Bfrag[1][kb], acc[rt][1], 0, 0, 0);
      }

    // ---- phase 1b: prefetch next-step x fragments ----
    {
      unsigned tn = (t + 1u) & 1023u;
      #pragma unroll
      for (int rt = 0; rt < 2; ++rt) {
        unsigned bblk = rh*2u + (unsigned)rt;
        #pragma unroll
        for (int kb = 0; kb < 4; ++kb) {
          size_t off = (((((size_t)xp*1024u + tn)*4u + (unsigned)kb)*4u + bblk)*512u) + lane*8u;
          xa[rt*4+kb] = *reinterpret_cast<const s16x8*>(xTf + off);
        }
      }
    }

    // ---- phase 1c: wait for domain h (per-wave spin, no cache maintenance) ----
    {
      const unsigned need = t;
      while (true) {
        unsigned fv = __hip_atomic_load(flagp + lane, __ATOMIC_RELAXED, __HIP_MEMORY_SCOPE_AGENT);
        if (__all(fv >= need)) break;
      }
      __builtin_amdgcn_sched_barrier(0);
    }

    // ---- phase 1d: h loads (coherent) + h MFMAs ----
    {
      union HF { s16x8 v; u64 u[2]; } hf[16];
      #pragma unroll
      for (int rt = 0; rt < 2; ++rt) {
        unsigned bblk = rh*2u + (unsigned)rt;
        #pragma unroll
        for (int kb = 0; kb < 8; ++kb) {
          size_t off = (((((size_t)par*4u + sg)*8u + (unsigned)kb)*4u + bblk)*512u) + lane*8u;
          u64* hp = (u64*)(hbuf + off);
          hf[rt*8+kb].u[0] = __hip_atomic_load(hp,     __ATOMIC_RELAXED, __HIP_MEMORY_SCOPE_AGENT);
          hf[rt*8+kb].u[1] = __hip_atomic_load(hp + 1, __ATOMIC_RELAXED, __HIP_MEMORY_SCOPE_AGENT);
        }
      }
      #pragma unroll
      for (int rt = 0; rt < 2; ++rt)
        #pragma unroll
        for (int kb = 0; kb < 8; ++kb) {
          acc[rt][0] = __builtin_amdgcn_mfma_f32_16x16x32_bf16(hf[rt*8+kb].v, Bfrag[0][4+kb], acc[rt][0], 0, 0, 0);
          acc[rt][1] = __builtin_amdgcn_mfma_f32_16x16x32_bf16(hf[rt*8+kb].v, Bfrag[1][4+kb], acc[rt][1], 0, 0, 0);
        }
    }

    // ---- phase 2: gates -> LDS ----
    #pragma unroll
    for (int rt = 0; rt < 2; ++rt)
      #pragma unroll
      for (int ct = 0; ct < 2; ++ct) {
        unsigned g = g0 + (unsigned)ct;
        unsigned idx = ((which*4u + g)*16u + (lane & 15u))*36u + (unsigned)rt*16u + (lane >> 4)*4u;
        *reinterpret_cast<f32x4*>(&gl[idx]) = acc[rt][ct];
      }
    __syncthreads();   // (A)

    // ---- phase 3: activations, c/h update, h -> global (coherent bf16) ----
    float hv[4];
    #pragma unroll
    for (int hq = 0; hq < 4; ++hq) {
      unsigned hc = a_q*4u + (unsigned)hq;
      unsigned base = (a_s*4u*16u + hc)*36u + a_r;
      float gi = gl[base + 0u*576u] + bias[hq][0];
      float gf = gl[base + 1u*576u] + bias[hq][1];
      float gg = gl[base + 2u*576u] + bias[hq][2];
      float go = gl[base + 3u*576u] + bias[hq][3];
      float ii = 1.f / (1.f + __expf(-gi));
      float ff = 1.f / (1.f + __expf(-gf));
      float eg = __expf(2.f * gg);
      float tg = 1.f - 2.f / (eg + 1.f);
      float oo = 1.f / (1.f + __expf(-go));
      float cn = ff * c[hq] + ii * tg;
      c[hq] = cn;
      float ec = __expf(2.f * cn);
      float tc = 1.f - 2.f / (ec + 1.f);
      hv[hq] = oo * tc;
    }
    {
      size_t off = ((((((size_t)(par^1u)*4u + a_sg)*8u + a_kbh)*4u + a_bblk)*4u + a_kg)*16u + a_row)*8u + a_j0;
      u64 pk = (u64)f2bf(hv[0]) | ((u64)f2bf(hv[1]) << 16)
             | ((u64)f2bf(hv[2]) << 32) | ((u64)f2bf(hv[3]) << 48);
      __hip_atomic_store((u64*)(hbuf + off), pk, __ATOMIC_RELAXED, __HIP_MEMORY_SCOPE_AGENT);
    }
    {
      unsigned hb = (a_s*32u + a_r)*20u + a_q*4u;
      f32x4 hvv = {hv[0], hv[1], hv[2], hv[3]};
      *reinterpret_cast<f32x4*>(&hout[hb]) = hvv;
    }

    // ---- signal: this wave's h stores are durable at the coherence point ----
    asm volatile("s_waitcnt vmcnt(0)" ::: "memory");
    if (lane == 0)
      __hip_atomic_store(flagp + myflag, t + 1u, __ATOMIC_RELAXED, __HIP_MEMORY_SCOPE_AGENT);
    __syncthreads();   // (B) hout ready for combine

    // ---- phase 4: pair combine -> LDS output staging ----
    #pragma unroll
    for (int kk = 0; kk < 2; ++kk) {
      unsigned item = tid*2u + (unsigned)kk;
      unsigned r = item >> 4, hc = item & 15u;
      float aV = hout[r*20u + hc];
      float bV = hout[(32u + r)*20u + hc];
      float oV = p ? (aV + bV) : (aV - bV);
      ob[item*20u + (t & 15u)] = oV;
    }

    // ---- flush staged output every 16 steps (coalesced 64B per location) ----
    if ((t & 15u) == 15u) {
      unsigned tb = t >> 4;
      #pragma unroll
      for (int kk = 0; kk < 2; ++kk) {
        unsigned item = tid*2u + (unsigned)kk;
        unsigned r = item >> 4, hc = item & 15u;
        size_t o = (((size_t)p*64u + rh*32u + r)*256u + cq*16u + hc)*1024u + (size_t)tb*16u;
        #pragma unroll
        for (int q = 0; q < 4; ++q)
          *reinterpret_cast<f32x4*>(out + o + (unsigned)q*4u) =
              *reinterpret_cast<f32x4*>(&ob[item*20u + (unsigned)q*4u]);
      }
    }
  }
}

extern "C" void kernel_launch(void* const* d_in, const int* in_sizes, int n_in,
                              void* d_out, int out_size, void* d_ws, size_t ws_size,
                              hipStream_t stream) {
  (void)in_sizes; (void)n_in; (void)out_size; (void)ws_size;
  const float* x     = (const float*)d_in[0];
  const float* Wih_r = (const float*)d_in[1];
  const float* Whh_r = (const float*)d_in[2];
  const float* bih_r = (const float*)d_in[3];
  const float* bhh_r = (const float*)d_in[4];
  const float* Wih_i = (const float*)d_in[5];
  const float* Whh_i = (const float*)d_in[6];
  const float* bih_i = (const float*)d_in[7];
  const float* bhh_i = (const float*)d_in[8];
  float* out = (float*)d_out;

  char* ws = (char*)d_ws;
  unsigned* flags = (unsigned*)(ws + 0);
  u16* hbuf     = (u16*)(ws + WS_HBUF);
  u16* xTf      = (u16*)(ws + WS_XTF);
  u16* Wf       = (u16*)(ws + WS_WF);
  float* bsv    = (float*)(ws + WS_BSUM);

  // zero flags + h0 parity buffers
  hipMemsetAsync(ws, 0, WS_HBUF + 262144u, stream);

  prep_x<<<8192, 256, 0, stream>>>(x, xTf);
  prep_w<<<384, 256, 0, stream>>>(Wih_r, Whh_r, Wih_i, Whh_i, Wf);
  prep_b<<<8, 256, 0, stream>>>(bih_r, bhh_r, bih_i, bhh_i, bsv);
  lstm_main<<<64, 256, 0, stream>>>(xTf, Wf, bsv, hbuf, flags, out);
}